// Round 8
// baseline (130.845 us; speedup 1.0000x reference)
//
#include <hip/hip_runtime.h>

// Problem constants
#define Gn 256
#define Nn 512
#define En 4096
#define Fn 64
#define Cn 16
#define ET (En + Nn)   // CSR slots including self-loops

typedef _Float16 halfv8 __attribute__((ext_vector_type(8)));
typedef _Float16 halfv4 __attribute__((ext_vector_type(4)));
typedef _Float16 halfv2 __attribute__((ext_vector_type(2)));
typedef float    f32x4  __attribute__((ext_vector_type(4)));

__device__ __forceinline__ float pk_norm(unsigned p) {
    return (float)__builtin_bit_cast(_Float16, (unsigned short)(p & 0xffffu));
}

#if __has_builtin(__builtin_amdgcn_fdot2)
__device__ __forceinline__ float fdot2_(halfv2 a, halfv2 b, float c) {
    return __builtin_amdgcn_fdot2(a, b, c, false);
}
#else
__device__ __forceinline__ float fdot2_(halfv2 a, halfv2 b, float c) {
    return c + (float)a[0] * (float)b[0] + (float)a[1] * (float)b[1];
}
#endif

struct H2x4 { halfv2 p0, p1, p2, p3; };   // constant-index pair view of halfv8

__device__ __forceinline__ float dot8(halfv8 l, halfv8 h, float c) {
    H2x4 L = __builtin_bit_cast(H2x4, l);
    H2x4 H = __builtin_bit_cast(H2x4, h);
    c = fdot2_(L.p0, H.p0, c);
    c = fdot2_(L.p1, H.p1, c);
    c = fdot2_(L.p2, H.p2, c);
    c = fdot2_(L.p3, H.p3, c);
    return c;
}

// ---------------- K0: lw fp32 -> f16 (re-done every call; ws is re-poisoned) ----
__global__ __launch_bounds__(256) void cvt_lw(const float* __restrict__ lw,
                                              _Float16* __restrict__ lwh) {
    int i = (blockIdx.x * 256 + threadIdx.x) * 2;    // float4 index, 131072 total
    #pragma unroll
    for (int r = 0; r < 2; ++r) {
        float4 v = *(const float4*)(lw + (size_t)(i + r) * 4);
        halfv4 h; h[0]=(_Float16)v.x; h[1]=(_Float16)v.y;
                  h[2]=(_Float16)v.z; h[3]=(_Float16)v.w;
        *(halfv4*)((char*)lwh + (size_t)(i + r) * 8) = h;
    }
}

// ---------------- K1: fully fused per-graph GCN ----------------
// One block per graph (256 = #CUs), 1024 thr = 16 waves, ~158.6 KB LDS.
// CSR build -> LDS-f16 gather -> MFMA conv (h natural-layout into the free
// x-staging buffer; NO global h round-trip) -> per-thread k-slice dot vs
// f16 lw streamed from L2 (1 MB/block; 32 blocks/XCD share it) -> in-block
// reduce + log_softmax. Kills R6's K2/K3 launches + 32 MB h HBM traffic.
__global__ __launch_bounds__(1024, 4) void gcn_fused(
    const float* __restrict__ x,       // [G,N,F]
    const int*   __restrict__ ei,      // [G,2,E]
    const float* __restrict__ w,       // [F_OUT,F_IN] = [64,64]
    const float* __restrict__ wbias,   // [64]
    const _Float16* __restrict__ lwh,  // ws: [C, N*F] f16
    const float* __restrict__ lbias,   // [C]
    float* __restrict__ out)           // [G,C]
{
    __shared__ unsigned short xs_h[Nn * Fn];  // 64 KB: f16 x; then f16 h (natural)
    __shared__ unsigned short xhs[Nn * Fn];   // 64 KB: f16 aggregated, swizzled
    __shared__ unsigned short wts[Fn * Fn];   // 8 KB: f16 w rows, swizzled
    __shared__ unsigned int   epk[ET + 8];    // 18.5 KB: (src<<16)|f16(norm)
    __shared__ float dinv[Nn];                // degree -> rsqrt; reused for reduce
    __shared__ int   cnt[Nn];                 // excl -> incl prefix
    __shared__ int   wsum[8];

    const int g    = blockIdx.x;
    const int tid  = threadIdx.x;
    const int lane = tid & 63;
    const int wid  = tid >> 6;

    const float* xg = x + (size_t)g * Nn * Fn;
    const int*   es = ei + (size_t)g * 2 * En;   // sources
    const int*   ed = es + En;                    // targets

    if (tid < Nn) dinv[tid] = 1.0f;               // self-loop counts as 1
    __syncthreads();

    // ---- degree atomics + stage x (f16) + stage w (f16, swizzled) ----
    for (int e = tid; e < En; e += 1024) atomicAdd(&dinv[ed[e]], 1.0f);
    #pragma unroll
    for (int it = 0; it < 8; ++it) {
        int idx = tid + it * 1024;                // float4 index (8192 total)
        float4 v = *(const float4*)(xg + idx * 4);
        halfv4 hv; hv[0]=(_Float16)v.x; hv[1]=(_Float16)v.y;
                   hv[2]=(_Float16)v.z; hv[3]=(_Float16)v.w;
        *(halfv4*)((char*)xs_h + idx * 8) = hv;   // natural [n][f] layout
    }
    {
        int o = tid >> 4, f0 = (tid & 15) * 4;    // 4096 elems / 1024 thr
        float4 v = *(const float4*)(w + o * Fn + f0);
        halfv4 hv; hv[0]=(_Float16)v.x; hv[1]=(_Float16)v.y;
                   hv[2]=(_Float16)v.z; hv[3]=(_Float16)v.w;
        int blk = f0 >> 3, hf = (f0 >> 2) & 1;    // 16B-block XOR swizzle by row
        *(halfv4*)((char*)wts + o * 128 + ((blk ^ (o & 7)) * 16) + hf * 8) = hv;
    }
    __syncthreads();

    // ---- per-node slot count (incl self) + dinv; exclusive prefix scan ----
    int c = 0;
    if (tid < Nn) { float d = dinv[tid]; c = (int)d; dinv[tid] = rsqrtf(d); }
    int v_ = c;
    #pragma unroll
    for (int off = 1; off < 64; off <<= 1) {
        int u = __shfl_up(v_, off, 64);
        if (lane >= off) v_ += u;
    }
    if (wid < 8 && lane == 63) wsum[wid] = v_;
    __syncthreads();
    if (tid == 0) { int a = 0; for (int i = 0; i < 8; ++i) { int t = wsum[i]; wsum[i] = a; a += t; } }
    __syncthreads();
    if (tid < Nn) cnt[tid] = v_ - c + wsum[wid];
    __syncthreads();

    // ---- CSR fill (edges + self-loops) with packed src|norm ----
    for (int e = tid; e < ET; e += 1024) {
        int s, t;
        if (e < En) { s = es[e]; t = ed[e]; } else { s = e - En; t = s; }
        float nrm = dinv[s] * dinv[t];
        int slot = atomicAdd(&cnt[t], 1);         // cnt becomes inclusive prefix
        unsigned short nb = __builtin_bit_cast(unsigned short, (_Float16)nrm);
        epk[slot] = ((unsigned)s << 16) | nb;
    }
    __syncthreads();

    // ---- gather: quarter-wave per target, all-LDS, 4-wide pipelined ----
    {
        const int qid = lane >> 4, fl = lane & 15;  // lane owns features fl*4..+3
        for (int r = 0; r < 8; ++r) {
            int t = r * 64 + wid * 4 + qid;
            int beg = (t == 0) ? 0 : cnt[t - 1];
            int end = cnt[t];
            float a0 = 0.f, a1 = 0.f, a2 = 0.f, a3 = 0.f;
            unsigned pA0 = epk[beg],     pA1 = epk[beg + 1];
            unsigned pA2 = epk[beg + 2], pA3 = epk[beg + 3];
            int j = beg;
            for (; j + 4 <= end; j += 4) {
                unsigned pB0 = epk[j + 4], pB1 = epk[j + 5];
                unsigned pB2 = epk[j + 6], pB3 = epk[j + 7];
                int s0 = pA0 >> 16, s1 = pA1 >> 16, s2 = pA2 >> 16, s3 = pA3 >> 16;
                float n0 = pk_norm(pA0), n1 = pk_norm(pA1);
                float n2 = pk_norm(pA2), n3 = pk_norm(pA3);
                halfv4 x0 = *(const halfv4*)((const char*)xs_h + s0 * 128 + fl * 8);
                halfv4 x1 = *(const halfv4*)((const char*)xs_h + s1 * 128 + fl * 8);
                halfv4 x2 = *(const halfv4*)((const char*)xs_h + s2 * 128 + fl * 8);
                halfv4 x3 = *(const halfv4*)((const char*)xs_h + s3 * 128 + fl * 8);
                a0 += n0 * (float)x0[0] + n1 * (float)x1[0] + n2 * (float)x2[0] + n3 * (float)x3[0];
                a1 += n0 * (float)x0[1] + n1 * (float)x1[1] + n2 * (float)x2[1] + n3 * (float)x3[1];
                a2 += n0 * (float)x0[2] + n1 * (float)x1[2] + n2 * (float)x2[2] + n3 * (float)x3[2];
                a3 += n0 * (float)x0[3] + n1 * (float)x1[3] + n2 * (float)x2[3] + n3 * (float)x3[3];
                pA0 = pB0; pA1 = pB1; pA2 = pB2; pA3 = pB3;
            }
            for (; j < end; ++j) {                  // tail (<=3)
                int s = pA0 >> 16;
                float nm = pk_norm(pA0);
                halfv4 xv = *(const halfv4*)((const char*)xs_h + s * 128 + fl * 8);
                a0 += nm * (float)xv[0]; a1 += nm * (float)xv[1];
                a2 += nm * (float)xv[2]; a3 += nm * (float)xv[3];
                pA0 = pA1; pA1 = pA2; pA2 = pA3;
            }
            halfv4 hv; hv[0]=(_Float16)a0; hv[1]=(_Float16)a1;
                       hv[2]=(_Float16)a2; hv[3]=(_Float16)a3;
            int dw = t * 32 + (((fl >> 1) ^ (t & 7)) * 4) + (fl & 1) * 2;
            *(halfv4*)((char*)xhs + dw * 4) = hv;
        }
    }
    __syncthreads();

    // ---- conv (transposed tiles): h = relu(W xh^T + b), natural into xs_h ----
    // A-frag = wts row o, B-frag = xhs row n. D: row=q*4+reg -> o, col=m -> n.
    // Lane's 4 D-values are o-contiguous -> one b64 natural write per tile
    // (xs_h's x content is dead after the gather; no race with xhs reads).
    {
        const int m = lane & 15, q = lane >> 4;
        #pragma unroll
        for (int j = 0; j < 8; ++j) {
            int idx = wid * 8 + j, tm = idx >> 2, to = idx & 3;
            int n = tm * 16 + m, o = to * 16 + m;
            halfv8 X0 = *(const halfv8*)((const char*)xhs + n * 128 + ((q       ^ (n & 7)) * 16));
            halfv8 X1 = *(const halfv8*)((const char*)xhs + n * 128 + (((4 + q) ^ (n & 7)) * 16));
            halfv8 W0 = *(const halfv8*)((const char*)wts + o * 128 + ((q       ^ (o & 7)) * 16));
            halfv8 W1 = *(const halfv8*)((const char*)wts + o * 128 + (((4 + q) ^ (o & 7)) * 16));
            f32x4 acc = {0.f, 0.f, 0.f, 0.f};
            acc = __builtin_amdgcn_mfma_f32_16x16x32_f16(W0, X0, acc, 0, 0, 0);
            acc = __builtin_amdgcn_mfma_f32_16x16x32_f16(W1, X1, acc, 0, 0, 0);
            float4 bq = *(const float4*)&wbias[to * 16 + q * 4];
            halfv4 hv;
            hv[0] = (_Float16)fmaxf(acc[0] + bq.x, 0.0f);
            hv[1] = (_Float16)fmaxf(acc[1] + bq.y, 0.0f);
            hv[2] = (_Float16)fmaxf(acc[2] + bq.z, 0.0f);
            hv[3] = (_Float16)fmaxf(acc[3] + bq.w, 0.0f);
            // natural: h[n][o_base..o_base+3], o_base = to*16 + q*4
            *(halfv4*)((char*)xs_h + n * 128 + (to * 16 + q * 4) * 2) = hv;
        }
    }
    __syncthreads();

    // ---- linear + log_softmax, fused in-block ----
    // Thread t owns k-slice [t*32, t*32+32) of flat h (k = n*64+o). h from LDS
    // (read once into regs), lwh streamed from global/L2. fp32 acc via fdot2.
    {
        const int k0 = tid * 32;
        halfv8 hr0 = *(const halfv8*)((const char*)xs_h + k0 * 2);
        halfv8 hr1 = *(const halfv8*)((const char*)xs_h + k0 * 2 + 16);
        halfv8 hr2 = *(const halfv8*)((const char*)xs_h + k0 * 2 + 32);
        halfv8 hr3 = *(const halfv8*)((const char*)xs_h + k0 * 2 + 48);

        float* wredf = dinv;                      // reuse (dinv dead): [16][16]
        #pragma unroll
        for (int cb = 0; cb < 4; ++cb) {          // 4 class-chunks of 4 -> low VGPR
            const halfv8* lp0 = (const halfv8*)(lwh + (size_t)(cb*4+0) * (Nn*Fn) + k0);
            const halfv8* lp1 = (const halfv8*)(lwh + (size_t)(cb*4+1) * (Nn*Fn) + k0);
            const halfv8* lp2 = (const halfv8*)(lwh + (size_t)(cb*4+2) * (Nn*Fn) + k0);
            const halfv8* lp3 = (const halfv8*)(lwh + (size_t)(cb*4+3) * (Nn*Fn) + k0);
            halfv8 l00=lp0[0], l01=lp0[1], l02=lp0[2], l03=lp0[3];
            halfv8 l10=lp1[0], l11=lp1[1], l12=lp1[2], l13=lp1[3];
            halfv8 l20=lp2[0], l21=lp2[1], l22=lp2[2], l23=lp2[3];
            halfv8 l30=lp3[0], l31=lp3[1], l32=lp3[2], l33=lp3[3];
            float a0 = 0.f, a1 = 0.f, a2 = 0.f, a3 = 0.f;
            a0 = dot8(l00, hr0, a0); a1 = dot8(l10, hr0, a1);
            a2 = dot8(l20, hr0, a2); a3 = dot8(l30, hr0, a3);
            a0 = dot8(l01, hr1, a0); a1 = dot8(l11, hr1, a1);
            a2 = dot8(l21, hr1, a2); a3 = dot8(l31, hr1, a3);
            a0 = dot8(l02, hr2, a0); a1 = dot8(l12, hr2, a1);
            a2 = dot8(l22, hr2, a2); a3 = dot8(l32, hr2, a3);
            a0 = dot8(l03, hr3, a0); a1 = dot8(l13, hr3, a1);
            a2 = dot8(l23, hr3, a2); a3 = dot8(l33, hr3, a3);

            // wave-reduce the 4 partials, deposit per-wave sums
            #pragma unroll
            for (int off = 32; off > 0; off >>= 1) {
                a0 += __shfl_down(a0, off, 64);
                a1 += __shfl_down(a1, off, 64);
                a2 += __shfl_down(a2, off, 64);
                a3 += __shfl_down(a3, off, 64);
            }
            if (lane == 0) {
                wredf[wid * 16 + cb * 4 + 0] = a0;
                wredf[wid * 16 + cb * 4 + 1] = a1;
                wredf[wid * 16 + cb * 4 + 2] = a2;
                wredf[wid * 16 + cb * 4 + 3] = a3;
            }
        }
        __syncthreads();

        if (wid == 0 && lane < Cn) {
            float v = lbias[lane];
            #pragma unroll
            for (int k = 0; k < 16; ++k) v += wredf[k * 16 + lane];
            float m = v;
            #pragma unroll
            for (int off = 8; off > 0; off >>= 1) m = fmaxf(m, __shfl_xor(m, off, 16));
            float ex = expf(v - m);
            float ssum = ex;
            #pragma unroll
            for (int off = 8; off > 0; off >>= 1) ssum += __shfl_xor(ssum, off, 16);
            out[g * Cn + lane] = v - m - logf(ssum);
        }
    }
}

extern "C" void kernel_launch(void* const* d_in, const int* in_sizes, int n_in,
                              void* d_out, int out_size, void* d_ws, size_t ws_size,
                              hipStream_t stream) {
    const float* x  = (const float*)d_in[0];
    const int*   ei = (const int*)d_in[1];
    const float* w  = (const float*)d_in[2];
    const float* wb = (const float*)d_in[3];
    const float* lw = (const float*)d_in[4];
    const float* lb = (const float*)d_in[5];
    float* out = (float*)d_out;

    _Float16* lwh = (_Float16*)d_ws;   // 1 MB f16 copy of lin_weight

    hipLaunchKernelGGL(cvt_lw, dim3(Gn), dim3(256), 0, stream, lw, lwh);
    hipLaunchKernelGGL(gcn_fused, dim3(Gn), dim3(1024), 0, stream,
                       x, ei, w, wb, lwh, lb, out);
}